// Round 8
// baseline (396.317 us; speedup 1.0000x reference)
//
#include <hip/hip_runtime.h>
#include <math.h>

#define B_   2
#define N_   2048
#define DIM_ 512
#define NH_  8
#define HD_  64
#define K_   32
#define PD_  16
#define TOK_ (B_*N_)     // 4096 rows
#define FFN_ 2048
#define QKV_ (3*DIM_)    // 1536
#define KV_  1024        // k|v bf16 row length

typedef __bf16 bf16x8 __attribute__((ext_vector_type(8)));
typedef float  f32x4  __attribute__((ext_vector_type(4)));

__device__ __forceinline__ unsigned short f2bf(float f) {
    unsigned int u = __float_as_uint(f);
    u = (u + 0x7fffu + ((u >> 16) & 1u)) >> 16;
    return (unsigned short)u;
}

__device__ __forceinline__ float bflo(unsigned u) { return __uint_as_float(u << 16); }
__device__ __forceinline__ float bfhi(unsigned u) { return __uint_as_float(u & 0xffff0000u); }

__device__ __forceinline__ float gelu_tanh(float x) {
    float x3 = x * x * x;
    return 0.5f * x * (1.f + tanhf(0.7978845608028654f * (x + 0.044715f * x3)));
}

__device__ __forceinline__ float tanh_fast(float x) {
    float e = __expf(2.f * x);
    return 1.f - 2.f / (e + 1.f);
}

__device__ __forceinline__ int lane_mbcnt(unsigned long long m) {
    return __builtin_amdgcn_mbcnt_hi((unsigned)(m >> 32),
           __builtin_amdgcn_mbcnt_lo((unsigned)m, 0));
}

// async global->LDS, 16B per lane. LDS dst must be wave-uniform base + lane*16.
#define GLOAD_LDS16(g, l) __builtin_amdgcn_global_load_lds(                        \
    (const __attribute__((address_space(1))) unsigned int*)(const void*)(g),       \
    (__attribute__((address_space(3))) unsigned int*)(void*)(l), 16, 0, 0)

// ---------------------------------------------------------------------------
// GEMM body: C[M,N] = A[M,Kd] @ Bt[N,Kd]^T, BK=64, 8-chunk XOR swizzle.
// LDS slot (r, sc) holds global 16B-chunk sc ^ (r&7) of row r -> fragment
// ds_read_b128 is 2-way bank aliased (free), staging stays lane-ordered.
// EPI: 0 +bias->fp32 ; 1 +bias+res->fp32 ; 2 gelu(+bias)->bf16
//      3 QKV split: col<512 -> q fp32 [row][512]; col>=512 -> kv bf16 [row][1024]
// ---------------------------------------------------------------------------
template<int EPI, int BM, int BN>
__device__ __forceinline__ void gemm_body(unsigned short* smem, int bx, int by,
                      const unsigned short* __restrict__ A,
                      const unsigned short* __restrict__ Bt,
                      const float* __restrict__ bias,
                      const float* __restrict__ res,
                      float* __restrict__ Cf,
                      unsigned short* __restrict__ Cb,
                      int N, int Kd)
{
    constexpr int WM = BM / 2;
    constexpr int WN = BN / 2;
    constexpr int FM = WM / 16;
    constexpr int FN = WN / 16;

    unsigned short* As_ = smem;            // BM rows x 128B
    unsigned short* Bs_ = smem + BM * 64;  // BN rows x 128B

    int t    = threadIdx.x;
    int lane = t & 63;
    int wid  = t >> 6;
    int wm   = wid >> 1, wn = wid & 1;
    int bm0  = by * BM;
    int bn0  = bx * BN;
    int quad = lane >> 4;
    int rlo  = lane & 15;

    f32x4 acc[FM][FN] = {};

    for (int k0 = 0; k0 < Kd; k0 += 64) {
#pragma unroll
        for (int l = 0; l < BM/32; l++) {
            int idx = l*256 + t;
            int r   = idx >> 3;
            int g   = (idx & 7) ^ (r & 7);
            GLOAD_LDS16(A + (size_t)(bm0 + r) * Kd + k0 + g*8, As_ + idx*8);
        }
#pragma unroll
        for (int l = 0; l < BN/32; l++) {
            int idx = l*256 + t;
            int r   = idx >> 3;
            int g   = (idx & 7) ^ (r & 7);
            GLOAD_LDS16(Bt + (size_t)(bn0 + r) * Kd + k0 + g*8, Bs_ + idx*8);
        }
        __syncthreads();

        bf16x8 af[FM][2], bfr[FN][2];
#pragma unroll
        for (int mi = 0; mi < FM; mi++) {
            int r = wm*WM + mi*16 + rlo;
#pragma unroll
            for (int s = 0; s < 2; s++)
                af[mi][s] = *(const bf16x8*)(As_ + r*64 + ((s*4 + quad) ^ (r & 7))*8);
        }
#pragma unroll
        for (int ni = 0; ni < FN; ni++) {
            int r = wn*WN + ni*16 + rlo;
#pragma unroll
            for (int s = 0; s < 2; s++)
                bfr[ni][s] = *(const bf16x8*)(Bs_ + r*64 + ((s*4 + quad) ^ (r & 7))*8);
        }
#pragma unroll
        for (int s = 0; s < 2; s++)
#pragma unroll
            for (int mi = 0; mi < FM; mi++)
#pragma unroll
                for (int ni = 0; ni < FN; ni++)
                    acc[mi][ni] = __builtin_amdgcn_mfma_f32_16x16x32_bf16(
                        af[mi][s], bfr[ni][s], acc[mi][ni], 0, 0, 0);
        __syncthreads();
    }

    // epilogue: D row = quad*4 + r, col = rlo within each 16x16 tile
#pragma unroll
    for (int mi = 0; mi < FM; mi++) {
#pragma unroll
        for (int ni = 0; ni < FN; ni++) {
            int col = bn0 + wn*WN + ni*16 + rlo;
            float bv = bias[col];
#pragma unroll
            for (int r = 0; r < 4; r++) {
                int row = bm0 + wm*WM + mi*16 + quad*4 + r;
                float val = acc[mi][ni][r] + bv;
                if (EPI == 1) val += res[(size_t)row * N + col];
                if (EPI == 2) {
                    val = gelu_tanh(val);
                    Cb[(size_t)row * N + col] = f2bf(val);
                } else if (EPI == 3) {
                    if (col < DIM_) Cf[(size_t)row * DIM_ + col] = val;
                    else            Cb[(size_t)row * KV_ + (col - DIM_)] = f2bf(val);
                } else {
                    Cf[(size_t)row * N + col] = val;
                }
            }
        }
    }
}

template<int EPI, int BM, int BN>
__global__ __launch_bounds__(256)
void gemm_bf16_kernel(const unsigned short* __restrict__ A,
                      const unsigned short* __restrict__ Bt,
                      const float* __restrict__ bias,
                      const float* __restrict__ res,
                      float* __restrict__ Cf,
                      unsigned short* __restrict__ Cb,
                      int N, int Kd)
{
    __shared__ __align__(16) unsigned short smem[(BM+BN)*64];
    gemm_body<EPI,BM,BN>(smem, blockIdx.x, blockIdx.y, A, Bt, bias, res, Cf, Cb, N, Kd);
}

// ---------------------------------------------------------------------------
// dist body: 2 waves per row (1024 dists each, 16/lane) reading TRANSPOSED
// positions (posT[b][d][j]) -> every load lane-coalesced. Local radix-select
// top-32 per wave; merge 64 candidates by exact rank (packed u64 keys ->
// jax.lax.top_k lower-index-first semantics).
// ---------------------------------------------------------------------------
__device__ __forceinline__ void dist_body(unsigned long long* cand,  // [2][64]
                      int id,
                      const float* __restrict__ pos,
                      const float* __restrict__ posT,
                      const float* __restrict__ pos_sq,
                      const float* __restrict__ c_ptr,
                      int* __restrict__ topk_idx, float* __restrict__ topk_dist)
{
    int wid  = threadIdx.x >> 6;      // 0..3
    int lane = threadIdx.x & 63;
    int rw   = wid >> 1;              // row within block
    int hw   = wid & 1;               // half within row
    int bi   = id * 2 + rw;           // 0..TOK_-1
    int b    = bi >> 11;              // / N_
    float c  = *c_ptr;
    float inv_sqrt_c = rsqrtf(c);

    float pi[16];
    {
        const float4* pi4 = (const float4*)(pos + (size_t)bi * PD_);
        float4 a0 = pi4[0], a1 = pi4[1], a2 = pi4[2], a3 = pi4[3];
        pi[0]=a0.x; pi[1]=a0.y; pi[2]=a0.z; pi[3]=a0.w;
        pi[4]=a1.x; pi[5]=a1.y; pi[6]=a1.z; pi[7]=a1.w;
        pi[8]=a2.x; pi[9]=a2.y; pi[10]=a2.z; pi[11]=a2.w;
        pi[12]=a3.x; pi[13]=a3.y; pi[14]=a3.z; pi[15]=a3.w;
    }
    float ni = pos_sq[bi];
    float omci = 1.f - c * ni;

    const float* pT  = posT + (size_t)b * 16 * N_;
    const float* sqb = pos_sq + b * N_;
    int jbase = hw * 1024;

    unsigned rb[16];
#pragma unroll
    for (int tt = 0; tt < 16; tt++) {
        int j = jbase + tt*64 + lane;
        float diff = 0.f;
#pragma unroll
        for (int d = 0; d < 16; d++) {
            float dd = pi[d] - pT[d * N_ + j];
            diff += dd * dd;
        }
        float den = fmaxf(omci * (1.f - c * sqb[j]), 1e-8f);
        float arg = fmaxf(1.f + 2.f * c * diff / den, 1.f + 1e-7f);
        rb[tt] = __float_as_uint(arg);   // arg >= 1.0 > 0: bits monotone in dist
    }

    // --- local radix select: T = 32nd-smallest bit pattern among this 1024 ---
    unsigned T = 0;
    for (int bit = 30; bit >= 0; --bit) {
        unsigned probe = T | (1u << bit);
        int cnt = 0;
#pragma unroll
        for (int tt = 0; tt < 16; tt++)
            cnt += __popcll(__ballot(rb[tt] < probe));
        if (cnt < K_) T = probe;
    }

    int cnt_lt = 0;
#pragma unroll
    for (int tt = 0; tt < 16; tt++)
        cnt_lt += __popcll(__ballot(rb[tt] < T));
    int m = K_ - cnt_lt;                  // equals (lowest j) to take

    // --- extraction of local top-32 as packed keys into LDS ---
    int ltbase = 0, eqbase = 0;
#pragma unroll
    for (int tt = 0; tt < 16; tt++) {
        bool is_lt = rb[tt] < T;
        bool is_eq = rb[tt] == T;
        unsigned long long mlt = __ballot(is_lt);
        unsigned long long meq = __ballot(is_eq);
        int plt = ltbase + lane_mbcnt(mlt);
        int peq = eqbase + lane_mbcnt(meq);
        unsigned long long key =
            ((unsigned long long)rb[tt] << 32) | (unsigned)(jbase + tt*64 + lane);
        if (is_lt)                 cand[rw*64 + hw*K_ + plt] = key;
        else if (is_eq && peq < m) cand[rw*64 + hw*K_ + cnt_lt + peq] = key;
        ltbase += __popcll(mlt);
        eqbase += __popcll(meq);
    }
    __syncthreads();

    // --- merge: exact rank of each of the 64 candidates ---
    if (hw == 0) {
        unsigned long long mykey = cand[rw*64 + lane];
        int rank = 0;
#pragma unroll 8
        for (int M = 0; M < 64; M++)
            rank += (cand[rw*64 + M] < mykey) ? 1 : 0;
        if (rank < K_) {
            unsigned rbv = (unsigned)(mykey >> 32);
            int      j   = (int)(mykey & 0xffffffffu);
            topk_idx [(size_t)bi * K_ + rank] = j;
            topk_dist[(size_t)bi * K_ + rank] = acoshf(__uint_as_float(rbv)) * inv_sqrt_c;
        }
    }
}

// ---------------------------------------------------------------------------
// FUSED: QKV GEMM (blocks 0..383) + dist/top-k (blocks 384..2431).
// Latency-bound dist waves co-schedule with barrier-bound GEMM waves.
// ---------------------------------------------------------------------------
__global__ __launch_bounds__(256)
void qkv_dist_kernel(const unsigned short* __restrict__ xn,
                     const unsigned short* __restrict__ qkvWt,
                     const float* __restrict__ qkv_b,
                     float* __restrict__ qf, unsigned short* __restrict__ kvb,
                     const float* __restrict__ pos, const float* __restrict__ posT,
                     const float* __restrict__ pos_sq, const float* __restrict__ c_ptr,
                     int* __restrict__ tk_i, float* __restrict__ tk_d)
{
    __shared__ __align__(16) unsigned short smem[16384];   // 32 KB
    if (blockIdx.x < 384) {
        gemm_body<3,128,128>(smem, blockIdx.x % 12, blockIdx.x / 12,
                             xn, qkvWt, qkv_b, nullptr, qf, kvb, QKV_, DIM_);
    } else {
        dist_body((unsigned long long*)smem, blockIdx.x - 384,
                  pos, posT, pos_sq, c_ptr, tk_i, tk_d);
    }
}

// ---------------------------------------------------------------------------
// FUSED prep: 6 weight transposes + bias3 pack + pos_sq/posT + LN1.
// id: [0,3072) transposes ; [3072,3078) bias ; [3078,3094) pos ; [3094,4118) LN1
// ---------------------------------------------------------------------------
__global__ void fused_prep_kernel(const float* __restrict__ Wq, const float* __restrict__ Wk,
                            const float* __restrict__ Wv, const float* __restrict__ Wo,
                            const float* __restrict__ W1, const float* __restrict__ W2,
                            const float* __restrict__ bq, const float* __restrict__ bk,
                            const float* __restrict__ bv,
                            unsigned short* __restrict__ qkvWt,
                            unsigned short* __restrict__ WoT,
                            unsigned short* __restrict__ W1T,
                            unsigned short* __restrict__ W2T,
                            float* __restrict__ qkv_b,
                            const float* __restrict__ pos,
                            float* __restrict__ pos_sq,
                            float* __restrict__ posT,
                            const float* __restrict__ x,
                            const float* __restrict__ ln1_scale,
                            const float* __restrict__ ln1_bias,
                            unsigned short* __restrict__ xn)
{
    int id = blockIdx.x;
    int t  = threadIdx.x;

    if (id >= 3094) {                 // LN1
        int wave = (id - 3094) * 4 + (t >> 6);
        int lane = t & 63;
        const float* xr = x + (size_t)wave * DIM_;
        float v[8];
        float s = 0.f;
#pragma unroll
        for (int i = 0; i < 8; i++) { v[i] = xr[lane + i*64]; s += v[i]; }
#pragma unroll
        for (int off = 32; off; off >>= 1) s += __shfl_xor(s, off);
        float mean = s * (1.f / DIM_);
        float vs = 0.f;
#pragma unroll
        for (int i = 0; i < 8; i++) { float d = v[i] - mean; vs += d*d; }
#pragma unroll
        for (int off = 32; off; off >>= 1) vs += __shfl_xor(vs, off);
        float inv = rsqrtf(vs * (1.f / DIM_) + 1e-6f);
        unsigned short* yr = xn + (size_t)wave * DIM_;
#pragma unroll
        for (int i = 0; i < 8; i++) {
            int cc = lane + i*64;
            yr[cc] = f2bf((v[i] - mean) * inv * ln1_scale[cc] + ln1_bias[cc]);
        }
        return;
    }
    if (id >= 3078) {                 // pos_sq + posT
        int i = (id - 3078) * 256 + t;
        int b = i >> 11, j = i & (N_ - 1);
        const float4* p = (const float4*)(pos + (size_t)i * PD_);
        float4 a0 = p[0], a1 = p[1], a2 = p[2], a3 = p[3];
        float pv[16] = {a0.x,a0.y,a0.z,a0.w, a1.x,a1.y,a1.z,a1.w,
                        a2.x,a2.y,a2.z,a2.w, a3.x,a3.y,a3.z,a3.w};
        float s = 0.f;
#pragma unroll
        for (int d = 0; d < 16; d++) s += pv[d]*pv[d];
        pos_sq[i] = s;
        float* pT = posT + (size_t)b * 16 * N_;
#pragma unroll
        for (int d = 0; d < 16; d++) pT[d * N_ + j] = pv[d];
        return;
    }
    if (id >= 3072) {                 // bias pack
        int i = (id - 3072) * 256 + t;
        if (i < DIM_)            qkv_b[i] = bq[i];
        else if (i < 2*DIM_)     qkv_b[i] = bk[i - DIM_];
        else                     qkv_b[i] = bv[i - 2*DIM_];
        return;
    }

    const float* W; unsigned short* Wt; int Kd, Nw, nx, ti;
    if      (id < 256)  { W = Wq; Wt = qkvWt;               Kd = 512;  Nw = 512;  nx = 16; ti = id; }
    else if (id < 512)  { W = Wk; Wt = qkvWt + 512*512;     Kd = 512;  Nw = 512;  nx = 16; ti = id - 256; }
    else if (id < 768)  { W = Wv; Wt = qkvWt + 2*512*512;   Kd = 512;  Nw = 512;  nx = 16; ti = id - 512; }
    else if (id < 1024) { W = Wo; Wt = WoT;                 Kd = 512;  Nw = 512;  nx = 16; ti = id - 768; }
    else if (id < 2048) { W = W1; Wt = W1T;                 Kd = 512;  Nw = 2048; nx = 64; ti = id - 1024; }
    else                { W = W2; Wt = W2T;                 Kd = 2048; Nw = 512;  nx = 16; ti = id - 2048; }

    __shared__ float tile[32][33];
    int n0 = (ti % nx) * 32, k0 = (ti / nx) * 32;
    int tx = t & 31, ty = t >> 5;
#pragma unroll
    for (int i = 0; i < 32; i += 8)
        tile[ty + i][tx] = W[(size_t)(k0 + ty + i) * Nw + n0 + tx];
    __syncthreads();
#pragma unroll
    for (int i = 0; i < 32; i += 8)
        Wt[(size_t)(n0 + ty + i) * Kd + k0 + tx] = f2bf(tile[tx][ty + i]);
}

// ---------------------------------------------------------------------------
// LayerNorm standalone (LN2)
// ---------------------------------------------------------------------------
__global__ void layernorm_kernel(const float* __restrict__ x,
                                 const float* __restrict__ scale,
                                 const float* __restrict__ bias,
                                 unsigned short* __restrict__ y)
{
    int wave = (blockIdx.x * blockDim.x + threadIdx.x) >> 6;
    int lane = threadIdx.x & 63;
    if (wave >= TOK_) return;
    const float* xr = x + (size_t)wave * DIM_;
    float v[8];
    float s = 0.f;
#pragma unroll
    for (int i = 0; i < 8; i++) { v[i] = xr[lane + i*64]; s += v[i]; }
#pragma unroll
    for (int off = 32; off; off >>= 1) s += __shfl_xor(s, off);
    float mean = s * (1.f / DIM_);
    float vs = 0.f;
#pragma unroll
    for (int i = 0; i < 8; i++) { float d = v[i] - mean; vs += d*d; }
#pragma unroll
    for (int off = 32; off; off >>= 1) vs += __shfl_xor(vs, off);
    float inv = rsqrtf(vs * (1.f / DIM_) + 1e-6f);
    unsigned short* yr = y + (size_t)wave * DIM_;
#pragma unroll
    for (int i = 0; i < 8; i++) {
        int c = lane + i*64;
        yr[c] = f2bf((v[i] - mean) * inv * scale[c] + bias[c]);
    }
}

// ---------------------------------------------------------------------------
// Sparse attention with bf16 K/V. One wave per (b,h,i).
// ---------------------------------------------------------------------------
__global__ __launch_bounds__(256)
void attn_kernel(const float* __restrict__ q,
                 const unsigned short* __restrict__ kv,
                 const int* __restrict__ topk_idx, const float* __restrict__ topk_dist,
                 const float* __restrict__ log_tau_p, const float* __restrict__ attn_scale_p,
                 unsigned int* __restrict__ out)   // bf16 pairs
{
    int gw   = (blockIdx.x * blockDim.x + threadIdx.x) >> 6;
    int lane = threadIdx.x & 63;
    if (gw >= B_ * NH_ * N_) return;
    int b = gw / (NH_ * N_);
    int r = gw % (NH_ * N_);
    int h = r / N_;
    int i = r % N_;
    int tok = b * N_ + i;

    float tau    = fmaxf(__expf(*log_tau_p), 1e-8f);
    float ascale = *attn_scale_p;

    const int*   idxp = topk_idx  + (size_t)tok * K_;
    const float* dstp = topk_dist + (size_t)tok * K_;
    int   my_idx  = idxp[lane & 31];
    float my_dist = dstp[lane & 31];

    int jj   = lane >> 1;
    int half = lane & 1;

    // q half: 32 floats
    const float4* qp = (const float4*)(q + (size_t)tok * DIM_ + h * HD_ + half * 32);
    float4 qv[8];
#pragma unroll
    for (int u = 0; u < 8; u++) qv[u] = qp[u];

    // k half (bf16): 32 shorts = 4 x 16B
    int nb = __shfl(my_idx, jj);
    const uint4* kp = (const uint4*)(kv + (size_t)(b * N_ + nb) * KV_ + h * HD_ + half * 32);
    float dot = 0.f;
#pragma unroll
    for (int u = 0; u < 4; u++) {
        uint4 kw = kp[u];
        dot += qv[2*u].x   * bflo(kw.x) + qv[2*u].y   * bfhi(kw.x)
             + qv[2*u].z   * bflo(kw.y) + qv[2*u].w   * bfhi(kw.y)
             + qv[2*u+1].x * bflo(kw.z) + qv[2*u+1].y * bfhi(kw.z)
             + qv[2*u+1].z * bflo(kw.w) + qv[2*u+1].w * bfhi(kw.w);
    }
    dot += __shfl_xor(dot, 1);   // full dot on both lanes of the pair

    float fs = dot * 0.125f;                        // 1/sqrt(64)
    float gs = -__shfl(my_dist, jj) / tau;
    float s  = ascale * tanh_fast(fs + gs);

    // softmax over the 32 scores (each duplicated on a lane pair)
    float mx = s;
#pragma unroll
    for (int off = 32; off; off >>= 1) mx = fmaxf(mx, __shfl_xor(mx, off));
    float e  = __expf(s - mx);
    float ec = half ? 0.f : e;
#pragma unroll
    for (int off = 32; off; off >>= 1) ec += __shfl_xor(ec, off);
    float inv = 1.f / ec;

    // V phase: dim pair d2 = 2*(lane&31); lane>=32 handles odd neighbors
    int dp    = lane & 31;
    int half2 = lane >> 5;
    const unsigned int* vb = (const unsigned int*)(kv + DIM_ + h * HD_) + dp;
    float ax = 0.f, ay = 0.f;
#pragma unroll
    for (int it = 0; it < 16; it++) {
        int t2 = half2 + 2*it;
        float w  = __shfl(e, t2 * 2) * inv;
        int   nj = __shfl(my_idx, t2);
        unsigned vv = vb[(size_t)(b * N_ + nj) * (KV_/2)];
        ax += w * bflo(vv);
        ay += w * bfhi(vv);
    }
    ax += __shfl_xor(ax, 32);
    ay += __shfl_xor(ay, 32);
    if (lane < 32) {
        unsigned pck = ((unsigned)f2bf(ay) << 16) | (unsigned)f2bf(ax);
        out[(size_t)tok * (DIM_/2) + h * (HD_/2) + dp] = pck;
    }
}

// ---------------------------------------------------------------------------
extern "C" void kernel_launch(void* const* d_in, const int* in_sizes, int n_in,
                              void* d_out, int out_size, void* d_ws, size_t ws_size,
                              hipStream_t stream)
{
    const float* x          = (const float*)d_in[0];
    const float* positions  = (const float*)d_in[1];
    const float* c_p        = (const float*)d_in[2];
    const float* Wq         = (const float*)d_in[3];
    const float* bq         = (const float*)d_in[4];
    const float* Wk         = (const float*)d_in[5];
    const float* bk         = (const float*)d_in[6];
    const float* Wv         = (const float*)d_in[7];
    const float* bv         = (const float*)d_in[8];
    const float* Wo         = (const float*)d_in[9];
    const float* bo         = (const float*)d_in[10];
    const float* W1         = (const float*)d_in[11];
    const float* b1         = (const float*)d_in[12];
    const float* W2         = (const float*)d_in[13];
    const float* b2         = (const float*)d_in[14];
    const float* ln1_scale  = (const float*)d_in[15];
    const float* ln1_bias   = (const float*)d_in[16];
    const float* ln2_scale  = (const float*)d_in[17];
    const float* ln2_bias   = (const float*)d_in[18];
    const float* log_tau    = (const float*)d_in[19];
    const float* attn_scale = (const float*)d_in[20];

    char* p = (char*)d_ws;
    unsigned short* qkvWt  = (unsigned short*)p; p += (size_t)QKV_ * DIM_ * 2;   // [1536][512] bf16
    unsigned short* WoT    = (unsigned short*)p; p += (size_t)DIM_ * DIM_ * 2;   // [512][512]
    unsigned short* W1T    = (unsigned short*)p; p += (size_t)FFN_ * DIM_ * 2;   // [2048][512]
    unsigned short* W2T    = (unsigned short*)p; p += (size_t)DIM_ * FFN_ * 2;   // [512][2048]
    float*          qkv_b  = (float*)p;          p += (size_t)QKV_ * 4;
    unsigned short* xn     = (unsigned short*)p; p += (size_t)TOK_ * DIM_ * 2;   // bf16
    float*          qf     = (float*)p;          p += (size_t)TOK_ * DIM_ * 4;   // fp32 q
    unsigned short* kvb    = (unsigned short*)p; p += (size_t)TOK_ * KV_ * 2;    // bf16 k|v
    unsigned short* attn_o = (unsigned short*)p; p += (size_t)TOK_ * DIM_ * 2;   // bf16
    float*          x1     = (float*)p;          p += (size_t)TOK_ * DIM_ * 4;
    unsigned short* x2n    = (unsigned short*)p; p += (size_t)TOK_ * DIM_ * 2;
    unsigned short* hbuf   = (unsigned short*)p; p += (size_t)TOK_ * FFN_ * 2;
    float*          pos_sq = (float*)p;          p += (size_t)TOK_ * 4;
    float*          posT   = (float*)p;          p += (size_t)B_ * 16 * N_ * 4;
    float*          tk_d   = (float*)p;          p += (size_t)TOK_ * K_ * 4;
    int*            tk_i   = (int*)p;            p += (size_t)TOK_ * K_ * 4;

    // --- fused prep: transposes + bias + pos_sq/posT + LN1 ---
    fused_prep_kernel<<<4118, 256, 0, stream>>>(Wq, Wk, Wv, Wo, W1, W2, bq, bk, bv,
                                                qkvWt, WoT, W1T, W2T, qkv_b,
                                                positions, pos_sq, posT,
                                                x, ln1_scale, ln1_bias, xn);

    // --- fused QKV GEMM (384 blocks) + dist/top-k (2048 blocks) ---
    qkv_dist_kernel<<<384 + TOK_/2, 256, 0, stream>>>(
        xn, qkvWt, qkv_b, qf, kvb,
        positions, posT, pos_sq, c_p, tk_i, tk_d);

    // --- sparse attention -> bf16 ---
    attn_kernel<<<(B_*NH_*N_)/4, 256, 0, stream>>>(qf, kvb, tk_i, tk_d,
                                                   log_tau, attn_scale,
                                                   (unsigned int*)attn_o);

    // --- x1 = x + attn_o @ Wo + bo (fp32), 64x64 tiles -> 512 blocks ---
    gemm_bf16_kernel<1,64,64><<<dim3(DIM_/64, TOK_/64), 256, 0, stream>>>(
        attn_o, WoT, bo, x, x1, nullptr, DIM_, DIM_);

    // --- LN2 -> bf16 ---
    layernorm_kernel<<<TOK_/4, 256, 0, stream>>>(x1, ln2_scale, ln2_bias, x2n);

    // --- FFN1: gelu(x2n @ W1 + b1) -> bf16 h, 128x128 -> 512 blocks ---
    gemm_bf16_kernel<2,128,128><<<dim3(FFN_/128, TOK_/128), 256, 0, stream>>>(
        x2n, W1T, b1, nullptr, nullptr, hbuf, FFN_, DIM_);

    // --- FFN2: out = x1 + h @ W2 + b2 (fp32), 64x64 tiles -> 512 blocks ---
    gemm_bf16_kernel<1,64,64><<<dim3(DIM_/64, TOK_/64), 256, 0, stream>>>(
        hbuf, W2T, b2, x1, (float*)d_out, nullptr, DIM_, FFN_);
}

// Round 9
// 306.584 us; speedup vs baseline: 1.2927x; 1.2927x over previous
//
#include <hip/hip_runtime.h>
#include <math.h>

#define B_   2
#define N_   2048
#define DIM_ 512
#define NH_  8
#define HD_  64
#define K_   32
#define PD_  16
#define TOK_ (B_*N_)     // 4096 rows
#define FFN_ 2048
#define QKV_ (3*DIM_)    // 1536
#define KV_  1024        // k|v bf16 row length

typedef __bf16 bf16x8 __attribute__((ext_vector_type(8)));
typedef float  f32x4  __attribute__((ext_vector_type(4)));

__device__ __forceinline__ unsigned short f2bf(float f) {
    unsigned int u = __float_as_uint(f);
    u = (u + 0x7fffu + ((u >> 16) & 1u)) >> 16;
    return (unsigned short)u;
}

__device__ __forceinline__ float bflo(unsigned u) { return __uint_as_float(u << 16); }
__device__ __forceinline__ float bfhi(unsigned u) { return __uint_as_float(u & 0xffff0000u); }

__device__ __forceinline__ float gelu_tanh(float x) {
    float x3 = x * x * x;
    return 0.5f * x * (1.f + tanhf(0.7978845608028654f * (x + 0.044715f * x3)));
}

__device__ __forceinline__ float tanh_fast(float x) {
    float e = __expf(2.f * x);
    return 1.f - 2.f / (e + 1.f);
}

__device__ __forceinline__ int lane_mbcnt(unsigned long long m) {
    return __builtin_amdgcn_mbcnt_hi((unsigned)(m >> 32),
           __builtin_amdgcn_mbcnt_lo((unsigned)m, 0));
}

// async global->LDS, 16B per lane. LDS dst must be wave-uniform base + lane*16.
#define GLOAD_LDS16(g, l) __builtin_amdgcn_global_load_lds(                        \
    (const __attribute__((address_space(1))) unsigned int*)(const void*)(g),       \
    (__attribute__((address_space(3))) unsigned int*)(void*)(l), 16, 0, 0)

// ---------------------------------------------------------------------------
// GEMM: C[M,N] = A[M,Kd] @ Bt[N,Kd]^T, BK=64, 8-chunk XOR swizzle (0 bank
// conflicts, staging lane-ordered for global_load_lds). 256 thr, 4 waves 2x2.
// EPI: 0 +bias->fp32 ; 1 +bias+res->fp32 ; 2 gelu(+bias)->bf16
//      3 QKV split: col<512 -> q fp32 [row][512]; col>=512 -> kv bf16 [row][1024]
// Tile sizes chosen for >=512 blocks (>=2 blocks/CU) so barrier drains of one
// block are covered by CU-mates (the R6 128x128/384-block config starved).
// ---------------------------------------------------------------------------
template<int EPI, int BM, int BN>
__global__ __launch_bounds__(256)
void gemm_bf16_kernel(const unsigned short* __restrict__ A,
                      const unsigned short* __restrict__ Bt,
                      const float* __restrict__ bias,
                      const float* __restrict__ res,
                      float* __restrict__ Cf,
                      unsigned short* __restrict__ Cb,
                      int N, int Kd)
{
    constexpr int WM = BM / 2;
    constexpr int WN = BN / 2;
    constexpr int FM = WM / 16;
    constexpr int FN = WN / 16;

    __shared__ __align__(16) unsigned short smem[(BM+BN)*64];
    unsigned short* As_ = smem;            // BM rows x 128B
    unsigned short* Bs_ = smem + BM * 64;  // BN rows x 128B

    int t    = threadIdx.x;
    int lane = t & 63;
    int wid  = t >> 6;
    int wm   = wid >> 1, wn = wid & 1;
    int bm0  = blockIdx.y * BM;
    int bn0  = blockIdx.x * BN;
    int quad = lane >> 4;
    int rlo  = lane & 15;

    f32x4 acc[FM][FN] = {};

    for (int k0 = 0; k0 < Kd; k0 += 64) {
#pragma unroll
        for (int l = 0; l < BM/32; l++) {
            int idx = l*256 + t;
            int r   = idx >> 3;
            int g   = (idx & 7) ^ (r & 7);
            GLOAD_LDS16(A + (size_t)(bm0 + r) * Kd + k0 + g*8, As_ + idx*8);
        }
#pragma unroll
        for (int l = 0; l < BN/32; l++) {
            int idx = l*256 + t;
            int r   = idx >> 3;
            int g   = (idx & 7) ^ (r & 7);
            GLOAD_LDS16(Bt + (size_t)(bn0 + r) * Kd + k0 + g*8, Bs_ + idx*8);
        }
        __syncthreads();

        bf16x8 af[FM][2], bfr[FN][2];
#pragma unroll
        for (int mi = 0; mi < FM; mi++) {
            int r = wm*WM + mi*16 + rlo;
#pragma unroll
            for (int s = 0; s < 2; s++)
                af[mi][s] = *(const bf16x8*)(As_ + r*64 + ((s*4 + quad) ^ (r & 7))*8);
        }
#pragma unroll
        for (int ni = 0; ni < FN; ni++) {
            int r = wn*WN + ni*16 + rlo;
#pragma unroll
            for (int s = 0; s < 2; s++)
                bfr[ni][s] = *(const bf16x8*)(Bs_ + r*64 + ((s*4 + quad) ^ (r & 7))*8);
        }
#pragma unroll
        for (int s = 0; s < 2; s++)
#pragma unroll
            for (int mi = 0; mi < FM; mi++)
#pragma unroll
                for (int ni = 0; ni < FN; ni++)
                    acc[mi][ni] = __builtin_amdgcn_mfma_f32_16x16x32_bf16(
                        af[mi][s], bfr[ni][s], acc[mi][ni], 0, 0, 0);
        __syncthreads();
    }

    // epilogue: D row = quad*4 + r, col = rlo within each 16x16 tile
#pragma unroll
    for (int mi = 0; mi < FM; mi++) {
#pragma unroll
        for (int ni = 0; ni < FN; ni++) {
            int col = bn0 + wn*WN + ni*16 + rlo;
            float bv = bias[col];
#pragma unroll
            for (int r = 0; r < 4; r++) {
                int row = bm0 + wm*WM + mi*16 + quad*4 + r;
                float val = acc[mi][ni][r] + bv;
                if (EPI == 1) val += res[(size_t)row * N + col];
                if (EPI == 2) {
                    val = gelu_tanh(val);
                    Cb[(size_t)row * N + col] = f2bf(val);
                } else if (EPI == 3) {
                    if (col < DIM_) Cf[(size_t)row * DIM_ + col] = val;
                    else            Cb[(size_t)row * KV_ + (col - DIM_)] = f2bf(val);
                } else {
                    Cf[(size_t)row * N + col] = val;
                }
            }
        }
    }
}

// ---------------------------------------------------------------------------
// Poincare dist + exact top-K, standalone (1 KB LDS, high occupancy).
// 2 waves per row (1024 dists each) reading TRANSPOSED positions
// (posT[b][d][j]) -> every load lane-coalesced. Local radix-select top-32 per
// wave; merge 64 candidates by exact rank (packed u64 keys -> jax.lax.top_k
// lower-index-first semantics). acosh only on winners.
// ---------------------------------------------------------------------------
__global__ __launch_bounds__(256)
void dist_topk_split_kernel(const float* __restrict__ pos,
                            const float* __restrict__ posT,
                            const float* __restrict__ pos_sq,
                            const float* __restrict__ c_ptr,
                            int* __restrict__ topk_idx, float* __restrict__ topk_dist)
{
    __shared__ unsigned long long cand[2][64];

    int wid  = threadIdx.x >> 6;      // 0..3
    int lane = threadIdx.x & 63;
    int rw   = wid >> 1;              // row within block
    int hw   = wid & 1;               // half within row
    int bi   = blockIdx.x * 2 + rw;   // 0..TOK_-1
    int b    = bi >> 11;              // / N_
    float c  = *c_ptr;
    float inv_sqrt_c = rsqrtf(c);

    float pi[16];
    {
        const float4* pi4 = (const float4*)(pos + (size_t)bi * PD_);
        float4 a0 = pi4[0], a1 = pi4[1], a2 = pi4[2], a3 = pi4[3];
        pi[0]=a0.x; pi[1]=a0.y; pi[2]=a0.z; pi[3]=a0.w;
        pi[4]=a1.x; pi[5]=a1.y; pi[6]=a1.z; pi[7]=a1.w;
        pi[8]=a2.x; pi[9]=a2.y; pi[10]=a2.z; pi[11]=a2.w;
        pi[12]=a3.x; pi[13]=a3.y; pi[14]=a3.z; pi[15]=a3.w;
    }
    float ni = pos_sq[bi];
    float omci = 1.f - c * ni;

    const float* pT  = posT + (size_t)b * 16 * N_;
    const float* sqb = pos_sq + b * N_;
    int jbase = hw * 1024;

    unsigned rb[16];
#pragma unroll
    for (int tt = 0; tt < 16; tt++) {
        int j = jbase + tt*64 + lane;
        float diff = 0.f;
#pragma unroll
        for (int d = 0; d < 16; d++) {
            float dd = pi[d] - pT[d * N_ + j];
            diff += dd * dd;
        }
        float den = fmaxf(omci * (1.f - c * sqb[j]), 1e-8f);
        float arg = fmaxf(1.f + 2.f * c * diff / den, 1.f + 1e-7f);
        rb[tt] = __float_as_uint(arg);   // arg >= 1.0 > 0: bits monotone in dist
    }

    // --- local radix select: T = 32nd-smallest bit pattern among this 1024 ---
    unsigned T = 0;
    for (int bit = 30; bit >= 0; --bit) {
        unsigned probe = T | (1u << bit);
        int cnt = 0;
#pragma unroll
        for (int tt = 0; tt < 16; tt++)
            cnt += __popcll(__ballot(rb[tt] < probe));
        if (cnt < K_) T = probe;
    }

    int cnt_lt = 0;
#pragma unroll
    for (int tt = 0; tt < 16; tt++)
        cnt_lt += __popcll(__ballot(rb[tt] < T));
    int m = K_ - cnt_lt;                  // equals (lowest j) to take

    // --- extraction of local top-32 as packed keys into LDS ---
    int ltbase = 0, eqbase = 0;
#pragma unroll
    for (int tt = 0; tt < 16; tt++) {
        bool is_lt = rb[tt] < T;
        bool is_eq = rb[tt] == T;
        unsigned long long mlt = __ballot(is_lt);
        unsigned long long meq = __ballot(is_eq);
        int plt = ltbase + lane_mbcnt(mlt);
        int peq = eqbase + lane_mbcnt(meq);
        unsigned long long key =
            ((unsigned long long)rb[tt] << 32) | (unsigned)(jbase + tt*64 + lane);
        if (is_lt)                 cand[rw][hw*K_ + plt] = key;
        else if (is_eq && peq < m) cand[rw][hw*K_ + cnt_lt + peq] = key;
        ltbase += __popcll(mlt);
        eqbase += __popcll(meq);
    }
    __syncthreads();

    // --- merge: exact rank of each of the 64 candidates ---
    if (hw == 0) {
        unsigned long long mykey = cand[rw][lane];
        int rank = 0;
#pragma unroll 8
        for (int M = 0; M < 64; M++)
            rank += (cand[rw][M] < mykey) ? 1 : 0;
        if (rank < K_) {
            unsigned rbv = (unsigned)(mykey >> 32);
            int      j   = (int)(mykey & 0xffffffffu);
            topk_idx [(size_t)bi * K_ + rank] = j;
            topk_dist[(size_t)bi * K_ + rank] = acoshf(__uint_as_float(rbv)) * inv_sqrt_c;
        }
    }
}

// ---------------------------------------------------------------------------
// FUSED prep: 6 weight transposes + bias3 pack + pos_sq/posT + LN1.
// id: [0,3072) transposes ; [3072,3078) bias ; [3078,3094) pos ; [3094,4118) LN1
// ---------------------------------------------------------------------------
__global__ void fused_prep_kernel(const float* __restrict__ Wq, const float* __restrict__ Wk,
                            const float* __restrict__ Wv, const float* __restrict__ Wo,
                            const float* __restrict__ W1, const float* __restrict__ W2,
                            const float* __restrict__ bq, const float* __restrict__ bk,
                            const float* __restrict__ bv,
                            unsigned short* __restrict__ qkvWt,
                            unsigned short* __restrict__ WoT,
                            unsigned short* __restrict__ W1T,
                            unsigned short* __restrict__ W2T,
                            float* __restrict__ qkv_b,
                            const float* __restrict__ pos,
                            float* __restrict__ pos_sq,
                            float* __restrict__ posT,
                            const float* __restrict__ x,
                            const float* __restrict__ ln1_scale,
                            const float* __restrict__ ln1_bias,
                            unsigned short* __restrict__ xn)
{
    int id = blockIdx.x;
    int t  = threadIdx.x;

    if (id >= 3094) {                 // LN1
        int wave = (id - 3094) * 4 + (t >> 6);
        int lane = t & 63;
        const float* xr = x + (size_t)wave * DIM_;
        float v[8];
        float s = 0.f;
#pragma unroll
        for (int i = 0; i < 8; i++) { v[i] = xr[lane + i*64]; s += v[i]; }
#pragma unroll
        for (int off = 32; off; off >>= 1) s += __shfl_xor(s, off);
        float mean = s * (1.f / DIM_);
        float vs = 0.f;
#pragma unroll
        for (int i = 0; i < 8; i++) { float d = v[i] - mean; vs += d*d; }
#pragma unroll
        for (int off = 32; off; off >>= 1) vs += __shfl_xor(vs, off);
        float inv = rsqrtf(vs * (1.f / DIM_) + 1e-6f);
        unsigned short* yr = xn + (size_t)wave * DIM_;
#pragma unroll
        for (int i = 0; i < 8; i++) {
            int cc = lane + i*64;
            yr[cc] = f2bf((v[i] - mean) * inv * ln1_scale[cc] + ln1_bias[cc]);
        }
        return;
    }
    if (id >= 3078) {                 // pos_sq + posT
        int i = (id - 3078) * 256 + t;
        int b = i >> 11, j = i & (N_ - 1);
        const float4* p = (const float4*)(pos + (size_t)i * PD_);
        float4 a0 = p[0], a1 = p[1], a2 = p[2], a3 = p[3];
        float pv[16] = {a0.x,a0.y,a0.z,a0.w, a1.x,a1.y,a1.z,a1.w,
                        a2.x,a2.y,a2.z,a2.w, a3.x,a3.y,a3.z,a3.w};
        float s = 0.f;
#pragma unroll
        for (int d = 0; d < 16; d++) s += pv[d]*pv[d];
        pos_sq[i] = s;
        float* pT = posT + (size_t)b * 16 * N_;
#pragma unroll
        for (int d = 0; d < 16; d++) pT[d * N_ + j] = pv[d];
        return;
    }
    if (id >= 3072) {                 // bias pack
        int i = (id - 3072) * 256 + t;
        if (i < DIM_)            qkv_b[i] = bq[i];
        else if (i < 2*DIM_)     qkv_b[i] = bk[i - DIM_];
        else                     qkv_b[i] = bv[i - 2*DIM_];
        return;
    }

    const float* W; unsigned short* Wt; int Kd, Nw, nx, ti;
    if      (id < 256)  { W = Wq; Wt = qkvWt;               Kd = 512;  Nw = 512;  nx = 16; ti = id; }
    else if (id < 512)  { W = Wk; Wt = qkvWt + 512*512;     Kd = 512;  Nw = 512;  nx = 16; ti = id - 256; }
    else if (id < 768)  { W = Wv; Wt = qkvWt + 2*512*512;   Kd = 512;  Nw = 512;  nx = 16; ti = id - 512; }
    else if (id < 1024) { W = Wo; Wt = WoT;                 Kd = 512;  Nw = 512;  nx = 16; ti = id - 768; }
    else if (id < 2048) { W = W1; Wt = W1T;                 Kd = 512;  Nw = 2048; nx = 64; ti = id - 1024; }
    else                { W = W2; Wt = W2T;                 Kd = 2048; Nw = 512;  nx = 16; ti = id - 2048; }

    __shared__ float tile[32][33];
    int n0 = (ti % nx) * 32, k0 = (ti / nx) * 32;
    int tx = t & 31, ty = t >> 5;
#pragma unroll
    for (int i = 0; i < 32; i += 8)
        tile[ty + i][tx] = W[(size_t)(k0 + ty + i) * Nw + n0 + tx];
    __syncthreads();
#pragma unroll
    for (int i = 0; i < 32; i += 8)
        Wt[(size_t)(n0 + ty + i) * Kd + k0 + tx] = f2bf(tile[tx][ty + i]);
}

// ---------------------------------------------------------------------------
// LayerNorm standalone (LN2)
// ---------------------------------------------------------------------------
__global__ void layernorm_kernel(const float* __restrict__ x,
                                 const float* __restrict__ scale,
                                 const float* __restrict__ bias,
                                 unsigned short* __restrict__ y)
{
    int wave = (blockIdx.x * blockDim.x + threadIdx.x) >> 6;
    int lane = threadIdx.x & 63;
    if (wave >= TOK_) return;
    const float* xr = x + (size_t)wave * DIM_;
    float v[8];
    float s = 0.f;
#pragma unroll
    for (int i = 0; i < 8; i++) { v[i] = xr[lane + i*64]; s += v[i]; }
#pragma unroll
    for (int off = 32; off; off >>= 1) s += __shfl_xor(s, off);
    float mean = s * (1.f / DIM_);
    float vs = 0.f;
#pragma unroll
    for (int i = 0; i < 8; i++) { float d = v[i] - mean; vs += d*d; }
#pragma unroll
    for (int off = 32; off; off >>= 1) vs += __shfl_xor(vs, off);
    float inv = rsqrtf(vs * (1.f / DIM_) + 1e-6f);
    unsigned short* yr = y + (size_t)wave * DIM_;
#pragma unroll
    for (int i = 0; i < 8; i++) {
        int c = lane + i*64;
        yr[c] = f2bf((v[i] - mean) * inv * scale[c] + bias[c]);
    }
}

// ---------------------------------------------------------------------------
// Sparse attention with bf16 K/V. One wave per (b,h,i).
// ---------------------------------------------------------------------------
__global__ __launch_bounds__(256)
void attn_kernel(const float* __restrict__ q,
                 const unsigned short* __restrict__ kv,
                 const int* __restrict__ topk_idx, const float* __restrict__ topk_dist,
                 const float* __restrict__ log_tau_p, const float* __restrict__ attn_scale_p,
                 unsigned int* __restrict__ out)   // bf16 pairs
{
    int gw   = (blockIdx.x * blockDim.x + threadIdx.x) >> 6;
    int lane = threadIdx.x & 63;
    if (gw >= B_ * NH_ * N_) return;
    int b = gw / (NH_ * N_);
    int r = gw % (NH_ * N_);
    int h = r / N_;
    int i = r % N_;
    int tok = b * N_ + i;

    float tau    = fmaxf(__expf(*log_tau_p), 1e-8f);
    float ascale = *attn_scale_p;

    const int*   idxp = topk_idx  + (size_t)tok * K_;
    const float* dstp = topk_dist + (size_t)tok * K_;
    int   my_idx  = idxp[lane & 31];
    float my_dist = dstp[lane & 31];

    int jj   = lane >> 1;
    int half = lane & 1;

    // q half: 32 floats
    const float4* qp = (const float4*)(q + (size_t)tok * DIM_ + h * HD_ + half * 32);
    float4 qv[8];
#pragma unroll
    for (int u = 0; u < 8; u++) qv[u] = qp[u];

    // k half (bf16): 32 shorts = 4 x 16B
    int nb = __shfl(my_idx, jj);
    const uint4* kp = (const uint4*)(kv + (size_t)(b * N_ + nb) * KV_ + h * HD_ + half * 32);
    float dot = 0.f;
#pragma unroll
    for (int u = 0; u < 4; u++) {
        uint4 kw = kp[u];
        dot += qv[2*u].x   * bflo(kw.x) + qv[2*u].y   * bfhi(kw.x)
             + qv[2*u].z   * bflo(kw.y) + qv[2*u].w   * bfhi(kw.y)
             + qv[2*u+1].x * bflo(kw.z) + qv[2*u+1].y * bfhi(kw.z)
             + qv[2*u+1].z * bflo(kw.w) + qv[2*u+1].w * bfhi(kw.w);
    }
    dot += __shfl_xor(dot, 1);   // full dot on both lanes of the pair

    float fs = dot * 0.125f;                        // 1/sqrt(64)
    float gs = -__shfl(my_dist, jj) / tau;
    float s  = ascale * tanh_fast(fs + gs);

    // softmax over the 32 scores (each duplicated on a lane pair)
    float mx = s;
#pragma unroll
    for (int off = 32; off; off >>= 1) mx = fmaxf(mx, __shfl_xor(mx, off));
    float e  = __expf(s - mx);
    float ec = half ? 0.f : e;
#pragma unroll
    for (int off = 32; off; off >>= 1) ec += __shfl_xor(ec, off);
    float inv = 1.f / ec;

    // V phase: dim pair d2 = 2*(lane&31); lane>=32 handles odd neighbors
    int dp    = lane & 31;
    int half2 = lane >> 5;
    const unsigned int* vb = (const unsigned int*)(kv + DIM_ + h * HD_) + dp;
    float ax = 0.f, ay = 0.f;
#pragma unroll
    for (int it = 0; it < 16; it++) {
        int t2 = half2 + 2*it;
        float w  = __shfl(e, t2 * 2) * inv;
        int   nj = __shfl(my_idx, t2);
        unsigned vv = vb[(size_t)(b * N_ + nj) * (KV_/2)];
        ax += w * bflo(vv);
        ay += w * bfhi(vv);
    }
    ax += __shfl_xor(ax, 32);
    ay += __shfl_xor(ay, 32);
    if (lane < 32) {
        unsigned pck = ((unsigned)f2bf(ay) << 16) | (unsigned)f2bf(ax);
        out[(size_t)tok * (DIM_/2) + h * (HD_/2) + dp] = pck;
    }
}

// ---------------------------------------------------------------------------
extern "C" void kernel_launch(void* const* d_in, const int* in_sizes, int n_in,
                              void* d_out, int out_size, void* d_ws, size_t ws_size,
                              hipStream_t stream)
{
    const float* x          = (const float*)d_in[0];
    const float* positions  = (const float*)d_in[1];
    const float* c_p        = (const float*)d_in[2];
    const float* Wq         = (const float*)d_in[3];
    const float* bq         = (const float*)d_in[4];
    const float* Wk         = (const float*)d_in[5];
    const float* bk         = (const float*)d_in[6];
    const float* Wv         = (const float*)d_in[7];
    const float* bv         = (const float*)d_in[8];
    const float* Wo         = (const float*)d_in[9];
    const float* bo         = (const float*)d_in[10];
    const float* W1         = (const float*)d_in[11];
    const float* b1         = (const float*)d_in[12];
    const float* W2         = (const float*)d_in[13];
    const float* b2         = (const float*)d_in[14];
    const float* ln1_scale  = (const float*)d_in[15];
    const float* ln1_bias   = (const float*)d_in[16];
    const float* ln2_scale  = (const float*)d_in[17];
    const float* ln2_bias   = (const float*)d_in[18];
    const float* log_tau    = (const float*)d_in[19];
    const float* attn_scale = (const float*)d_in[20];

    char* p = (char*)d_ws;
    unsigned short* qkvWt  = (unsigned short*)p; p += (size_t)QKV_ * DIM_ * 2;   // [1536][512] bf16
    unsigned short* WoT    = (unsigned short*)p; p += (size_t)DIM_ * DIM_ * 2;   // [512][512]
    unsigned short* W1T    = (unsigned short*)p; p += (size_t)FFN_ * DIM_ * 2;   // [2048][512]
    unsigned short* W2T    = (unsigned short*)p; p += (size_t)DIM_ * FFN_ * 2;   // [512][2048]
    float*          qkv_b  = (float*)p;          p += (size_t)QKV_ * 4;
    unsigned short* xn     = (unsigned short*)p; p += (size_t)TOK_ * DIM_ * 2;   // bf16
    float*          qf     = (float*)p;          p += (size_t)TOK_ * DIM_ * 4;   // fp32 q
    unsigned short* kvb    = (unsigned short*)p; p += (size_t)TOK_ * KV_ * 2;    // bf16 k|v
    unsigned short* attn_o = (unsigned short*)p; p += (size_t)TOK_ * DIM_ * 2;   // bf16
    float*          x1     = (float*)p;          p += (size_t)TOK_ * DIM_ * 4;
    unsigned short* x2n    = (unsigned short*)p; p += (size_t)TOK_ * DIM_ * 2;
    unsigned short* hbuf   = (unsigned short*)p; p += (size_t)TOK_ * FFN_ * 2;
    float*          pos_sq = (float*)p;          p += (size_t)TOK_ * 4;
    float*          posT   = (float*)p;          p += (size_t)B_ * 16 * N_ * 4;
    float*          tk_d   = (float*)p;          p += (size_t)TOK_ * K_ * 4;
    int*            tk_i   = (int*)p;            p += (size_t)TOK_ * K_ * 4;

    // --- fused prep: transposes + bias + pos_sq/posT + LN1 ---
    fused_prep_kernel<<<4118, 256, 0, stream>>>(Wq, Wk, Wv, Wo, W1, W2, bq, bk, bv,
                                                qkvWt, WoT, W1T, W2T, qkv_b,
                                                positions, pos_sq, posT,
                                                x, ln1_scale, ln1_bias, xn);

    // --- QKV GEMM: 64x128 tiles -> 768 blocks (3/CU) ---
    gemm_bf16_kernel<3,64,128><<<dim3(QKV_/128, TOK_/64), 256, 0, stream>>>(
        xn, qkvWt, qkv_b, nullptr, qf, kvb, QKV_, DIM_);

    // --- distances + top-k (2 waves/row, posT coalesced, 1 KB LDS) ---
    dist_topk_split_kernel<<<TOK_/2, 256, 0, stream>>>(positions, posT, pos_sq,
                                                       c_p, tk_i, tk_d);

    // --- sparse attention -> bf16 ---
    attn_kernel<<<(B_*NH_*N_)/4, 256, 0, stream>>>(qf, kvb, tk_i, tk_d,
                                                   log_tau, attn_scale,
                                                   (unsigned int*)attn_o);

    // --- x1 = x + attn_o @ Wo + bo (fp32), 64x64 -> 512 blocks ---
    gemm_bf16_kernel<1,64,64><<<dim3(DIM_/64, TOK_/64), 256, 0, stream>>>(
        attn_o, WoT, bo, x, x1, nullptr, DIM_, DIM_);

    // --- LN2 -> bf16 ---
    layernorm_kernel<<<TOK_/4, 256, 0, stream>>>(x1, ln2_scale, ln2_bias, x2n);

    // --- FFN1: gelu(x2n @ W1 + b1) -> bf16 h, 64x128 -> 1024 blocks ---
    gemm_bf16_kernel<2,64,128><<<dim3(FFN_/128, TOK_/64), 256, 0, stream>>>(
        x2n, W1T, b1, nullptr, nullptr, hbuf, FFN_, DIM_);

    // --- FFN2: out = x1 + h @ W2 + b2 (fp32), 64x64 -> 512 blocks ---
    gemm_bf16_kernel<1,64,64><<<dim3(DIM_/64, TOK_/64), 256, 0, stream>>>(
        hbuf, W2T, b2, x1, (float*)d_out, nullptr, DIM_, FFN_);
}

// Round 10
// 254.458 us; speedup vs baseline: 1.5575x; 1.2049x over previous
//
#include <hip/hip_runtime.h>
#include <math.h>

#define B_   2
#define N_   2048
#define DIM_ 512
#define NH_  8
#define HD_  64
#define K_   32
#define PD_  16
#define TOK_ (B_*N_)     // 4096 rows
#define FFN_ 2048
#define QKV_ (3*DIM_)    // 1536
#define KV_  1024        // k|v bf16 row length

typedef __bf16 bf16x8 __attribute__((ext_vector_type(8)));
typedef float  f32x4  __attribute__((ext_vector_type(4)));

__device__ __forceinline__ unsigned short f2bf(float f) {
    unsigned int u = __float_as_uint(f);
    u = (u + 0x7fffu + ((u >> 16) & 1u)) >> 16;
    return (unsigned short)u;
}

__device__ __forceinline__ float bflo(unsigned u) { return __uint_as_float(u << 16); }
__device__ __forceinline__ float bfhi(unsigned u) { return __uint_as_float(u & 0xffff0000u); }

__device__ __forceinline__ float gelu_tanh(float x) {
    float x3 = x * x * x;
    return 0.5f * x * (1.f + tanhf(0.7978845608028654f * (x + 0.044715f * x3)));
}

__device__ __forceinline__ float tanh_fast(float x) {
    float e = __expf(2.f * x);
    return 1.f - 2.f / (e + 1.f);
}

__device__ __forceinline__ int lane_mbcnt(unsigned long long m) {
    return __builtin_amdgcn_mbcnt_hi((unsigned)(m >> 32),
           __builtin_amdgcn_mbcnt_lo((unsigned)m, 0));
}

// async global->LDS, 16B per lane. LDS dst must be wave-uniform base + lane*16.
#define GLOAD_LDS16(g, l) __builtin_amdgcn_global_load_lds(                        \
    (const __attribute__((address_space(1))) unsigned int*)(const void*)(g),       \
    (__attribute__((address_space(3))) unsigned int*)(void*)(l), 16, 0, 0)

// ---------------------------------------------------------------------------
// GEMM: C[M,N] = A[M,Kd] @ Bt[N,Kd]^T, BK=64, 8-chunk XOR swizzle (0 bank
// conflicts, staging lane-ordered for global_load_lds). 256 thr, 4 waves 2x2.
// EPI: 0 +bias->fp32 ; 1 +bias+res->fp32 ; 2 gelu(+bias)->bf16
//      3 QKV split: col<512 -> q fp32 [row][512]; col>=512 -> kv bf16 [row][1024]
// ---------------------------------------------------------------------------
template<int EPI, int BM, int BN>
__global__ __launch_bounds__(256)
void gemm_bf16_kernel(const unsigned short* __restrict__ A,
                      const unsigned short* __restrict__ Bt,
                      const float* __restrict__ bias,
                      const float* __restrict__ res,
                      float* __restrict__ Cf,
                      unsigned short* __restrict__ Cb,
                      int N, int Kd)
{
    constexpr int WM = BM / 2;
    constexpr int WN = BN / 2;
    constexpr int FM = WM / 16;
    constexpr int FN = WN / 16;

    __shared__ __align__(16) unsigned short smem[(BM+BN)*64];
    unsigned short* As_ = smem;            // BM rows x 128B
    unsigned short* Bs_ = smem + BM * 64;  // BN rows x 128B

    int t    = threadIdx.x;
    int lane = t & 63;
    int wid  = t >> 6;
    int wm   = wid >> 1, wn = wid & 1;
    int bm0  = blockIdx.y * BM;
    int bn0  = blockIdx.x * BN;
    int quad = lane >> 4;
    int rlo  = lane & 15;

    f32x4 acc[FM][FN] = {};

    for (int k0 = 0; k0 < Kd; k0 += 64) {
#pragma unroll
        for (int l = 0; l < BM/32; l++) {
            int idx = l*256 + t;
            int r   = idx >> 3;
            int g   = (idx & 7) ^ (r & 7);
            GLOAD_LDS16(A + (size_t)(bm0 + r) * Kd + k0 + g*8, As_ + idx*8);
        }
#pragma unroll
        for (int l = 0; l < BN/32; l++) {
            int idx = l*256 + t;
            int r   = idx >> 3;
            int g   = (idx & 7) ^ (r & 7);
            GLOAD_LDS16(Bt + (size_t)(bn0 + r) * Kd + k0 + g*8, Bs_ + idx*8);
        }
        __syncthreads();

        bf16x8 af[FM][2], bfr[FN][2];
#pragma unroll
        for (int mi = 0; mi < FM; mi++) {
            int r = wm*WM + mi*16 + rlo;
#pragma unroll
            for (int s = 0; s < 2; s++)
                af[mi][s] = *(const bf16x8*)(As_ + r*64 + ((s*4 + quad) ^ (r & 7))*8);
        }
#pragma unroll
        for (int ni = 0; ni < FN; ni++) {
            int r = wn*WN + ni*16 + rlo;
#pragma unroll
            for (int s = 0; s < 2; s++)
                bfr[ni][s] = *(const bf16x8*)(Bs_ + r*64 + ((s*4 + quad) ^ (r & 7))*8);
        }
#pragma unroll
        for (int s = 0; s < 2; s++)
#pragma unroll
            for (int mi = 0; mi < FM; mi++)
#pragma unroll
                for (int ni = 0; ni < FN; ni++)
                    acc[mi][ni] = __builtin_amdgcn_mfma_f32_16x16x32_bf16(
                        af[mi][s], bfr[ni][s], acc[mi][ni], 0, 0, 0);
        __syncthreads();
    }

    // epilogue: D row = quad*4 + r, col = rlo within each 16x16 tile
#pragma unroll
    for (int mi = 0; mi < FM; mi++) {
#pragma unroll
        for (int ni = 0; ni < FN; ni++) {
            int col = bn0 + wn*WN + ni*16 + rlo;
            float bv = bias[col];
#pragma unroll
            for (int r = 0; r < 4; r++) {
                int row = bm0 + wm*WM + mi*16 + quad*4 + r;
                float val = acc[mi][ni][r] + bv;
                if (EPI == 1) val += res[(size_t)row * N + col];
                if (EPI == 2) {
                    val = gelu_tanh(val);
                    Cb[(size_t)row * N + col] = f2bf(val);
                } else if (EPI == 3) {
                    if (col < DIM_) Cf[(size_t)row * DIM_ + col] = val;
                    else            Cb[(size_t)row * KV_ + (col - DIM_)] = f2bf(val);
                } else {
                    Cf[(size_t)row * N + col] = val;
                }
            }
        }
    }
}

// ---------------------------------------------------------------------------
// Poincare dist + exact top-K. 2 waves per row; each wave: 1024 dists.
// Lane owns 4 CONSECUTIVE j per group: j = jbase + jg*256 + lane*4 + jj
// -> posT loads are fully-coalesced float4 (64 dwordx4/wave, 1KB/inst).
// Rank = pre-acosh "arg" bits (monotone). Radix select with common-prefix
// skip; counts via ballot + scalar popcount. Extraction: lt pass (order
// irrelevant, merge re-ranks) + eq pass in ascending-j order (exact
// jax.lax.top_k lower-index-first). Merge: 64 candidates, exact rank by
// packed (rb,j) u64 key. acosh only on the 32 winners.
// ---------------------------------------------------------------------------
__global__ __launch_bounds__(256)
void dist_topk_split_kernel(const float* __restrict__ pos,
                            const float* __restrict__ posT,
                            const float* __restrict__ pos_sq,
                            const float* __restrict__ c_ptr,
                            int* __restrict__ topk_idx, float* __restrict__ topk_dist)
{
    __shared__ unsigned long long cand[2][64];

    int wid  = threadIdx.x >> 6;      // 0..3
    int lane = threadIdx.x & 63;
    int rw   = wid >> 1;              // row within block
    int hw   = wid & 1;               // half within row
    int bi   = blockIdx.x * 2 + rw;   // 0..TOK_-1
    int b    = bi >> 11;              // / N_
    float c  = *c_ptr;
    float inv_sqrt_c = rsqrtf(c);

    float pi[16];
    {
        const float4* pi4 = (const float4*)(pos + (size_t)bi * PD_);
        float4 a0 = pi4[0], a1 = pi4[1], a2 = pi4[2], a3 = pi4[3];
        pi[0]=a0.x; pi[1]=a0.y; pi[2]=a0.z; pi[3]=a0.w;
        pi[4]=a1.x; pi[5]=a1.y; pi[6]=a1.z; pi[7]=a1.w;
        pi[8]=a2.x; pi[9]=a2.y; pi[10]=a2.z; pi[11]=a2.w;
        pi[12]=a3.x; pi[13]=a3.y; pi[14]=a3.z; pi[15]=a3.w;
    }
    float ni = pos_sq[bi];
    float omci = 1.f - c * ni;

    const float* pT  = posT + (size_t)b * 16 * N_;
    const float* sqb = pos_sq + b * N_;
    int jbase = hw * 1024;
    int j0l   = jbase + lane * 4;

    unsigned rb[16];
#pragma unroll
    for (int jg = 0; jg < 4; jg++) {
        int j0 = j0l + jg * 256;
        float dfx = 0.f, dfy = 0.f, dfz = 0.f, dfw = 0.f;
#pragma unroll
        for (int d = 0; d < 16; d++) {
            float4 v = *(const float4*)(pT + d * N_ + j0);
            float dx = pi[d]-v.x, dy = pi[d]-v.y, dz = pi[d]-v.z, dw = pi[d]-v.w;
            dfx += dx*dx; dfy += dy*dy; dfz += dz*dz; dfw += dw*dw;
        }
        float4 sq = *(const float4*)(sqb + j0);
        float dfa[4] = {dfx, dfy, dfz, dfw};
        float sqa[4] = {sq.x, sq.y, sq.z, sq.w};
#pragma unroll
        for (int jj = 0; jj < 4; jj++) {
            float den = fmaxf(omci * (1.f - c * sqa[jj]), 1e-8f);
            float arg = fmaxf(1.f + 2.f * c * dfa[jj] / den, 1.f + 1e-7f);
            rb[jg*4 + jj] = __float_as_uint(arg);   // >= 0x3F800000, monotone
        }
    }

    // --- common-prefix skip: AND/OR across all 1024 values ---
    unsigned band = rb[0], bor = rb[0];
#pragma unroll
    for (int tt = 1; tt < 16; tt++) { band &= rb[tt]; bor |= rb[tt]; }
#pragma unroll
    for (int off = 32; off; off >>= 1) {
        band &= __shfl_xor(band, off);
        bor  |= __shfl_xor(bor,  off);
    }
    unsigned diffb = band ^ bor;
    int hib = diffb ? (31 - __clz(diffb)) : -1;   // bit31 never differs (arg>0)
    unsigned T = (hib >= 0) ? (band & ~((1u << (hib+1)) - 1u)) : band;

    // --- radix select from highest differing bit ---
    for (int bit = hib; bit >= 0; --bit) {
        unsigned probe = T | (1u << bit);
        int cnt = 0;
#pragma unroll
        for (int tt = 0; tt < 16; tt++)
            cnt += __popcll(__ballot(rb[tt] < probe));
        if (cnt < K_) T = probe;
    }

    int cnt_lt = 0;
#pragma unroll
    for (int tt = 0; tt < 16; tt++)
        cnt_lt += __popcll(__ballot(rb[tt] < T));
    int m = K_ - cnt_lt;                  // equals (lowest j) to take

    // --- pass 1: all lt elements (order irrelevant; merge re-ranks) ---
    int ltpos = 0;
#pragma unroll
    for (int tt = 0; tt < 16; tt++) {
        bool is_lt = rb[tt] < T;
        unsigned long long mlt = __ballot(is_lt);
        int p = ltpos + lane_mbcnt(mlt);
        if (is_lt) {
            int j = jbase + (tt >> 2)*256 + lane*4 + (tt & 3);
            cand[rw][hw*K_ + p] = ((unsigned long long)rb[tt] << 32) | (unsigned)j;
        }
        ltpos += __popcll(mlt);
    }

    // --- pass 2: first m equals in ASCENDING-j order (jg, lane, jj) ---
    int eqpos = 0;
#pragma unroll
    for (int jg = 0; jg < 4; jg++) {
        bool iseq[4]; unsigned long long meq[4]; int bel[4];
#pragma unroll
        for (int jj = 0; jj < 4; jj++) {
            iseq[jj] = (rb[jg*4+jj] == T);
            meq[jj]  = __ballot(iseq[jj]);
            bel[jj]  = lane_mbcnt(meq[jj]);
        }
        int lane_prefix = bel[0] + bel[1] + bel[2] + bel[3];
        int within = 0;
#pragma unroll
        for (int jj = 0; jj < 4; jj++) {
            int p = eqpos + lane_prefix + within;
            if (iseq[jj] && p < m) {
                int j = jbase + jg*256 + lane*4 + jj;
                cand[rw][hw*K_ + cnt_lt + p] =
                    ((unsigned long long)rb[jg*4+jj] << 32) | (unsigned)j;
            }
            within += iseq[jj] ? 1 : 0;
        }
        eqpos += __popcll(meq[0]) + __popcll(meq[1]) + __popcll(meq[2]) + __popcll(meq[3]);
    }
    __syncthreads();

    // --- merge: exact rank of each of the 64 candidates ---
    if (hw == 0) {
        unsigned long long mykey = cand[rw][lane];
        int rank = 0;
#pragma unroll 8
        for (int M = 0; M < 64; M++)
            rank += (cand[rw][M] < mykey) ? 1 : 0;
        if (rank < K_) {
            unsigned rbv = (unsigned)(mykey >> 32);
            int      j   = (int)(mykey & 0xffffffffu);
            topk_idx [(size_t)bi * K_ + rank] = j;
            topk_dist[(size_t)bi * K_ + rank] = acoshf(__uint_as_float(rbv)) * inv_sqrt_c;
        }
    }
}

// ---------------------------------------------------------------------------
// FUSED prep: 6 weight transposes + bias3 pack + pos_sq/posT + LN1.
// id: [0,3072) transposes ; [3072,3078) bias ; [3078,3094) pos ; [3094,4118) LN1
// ---------------------------------------------------------------------------
__global__ void fused_prep_kernel(const float* __restrict__ Wq, const float* __restrict__ Wk,
                            const float* __restrict__ Wv, const float* __restrict__ Wo,
                            const float* __restrict__ W1, const float* __restrict__ W2,
                            const float* __restrict__ bq, const float* __restrict__ bk,
                            const float* __restrict__ bv,
                            unsigned short* __restrict__ qkvWt,
                            unsigned short* __restrict__ WoT,
                            unsigned short* __restrict__ W1T,
                            unsigned short* __restrict__ W2T,
                            float* __restrict__ qkv_b,
                            const float* __restrict__ pos,
                            float* __restrict__ pos_sq,
                            float* __restrict__ posT,
                            const float* __restrict__ x,
                            const float* __restrict__ ln1_scale,
                            const float* __restrict__ ln1_bias,
                            unsigned short* __restrict__ xn)
{
    int id = blockIdx.x;
    int t  = threadIdx.x;

    if (id >= 3094) {                 // LN1
        int wave = (id - 3094) * 4 + (t >> 6);
        int lane = t & 63;
        const float* xr = x + (size_t)wave * DIM_;
        float v[8];
        float s = 0.f;
#pragma unroll
        for (int i = 0; i < 8; i++) { v[i] = xr[lane + i*64]; s += v[i]; }
#pragma unroll
        for (int off = 32; off; off >>= 1) s += __shfl_xor(s, off);
        float mean = s * (1.f / DIM_);
        float vs = 0.f;
#pragma unroll
        for (int i = 0; i < 8; i++) { float d = v[i] - mean; vs += d*d; }
#pragma unroll
        for (int off = 32; off; off >>= 1) vs += __shfl_xor(vs, off);
        float inv = rsqrtf(vs * (1.f / DIM_) + 1e-6f);
        unsigned short* yr = xn + (size_t)wave * DIM_;
#pragma unroll
        for (int i = 0; i < 8; i++) {
            int cc = lane + i*64;
            yr[cc] = f2bf((v[i] - mean) * inv * ln1_scale[cc] + ln1_bias[cc]);
        }
        return;
    }
    if (id >= 3078) {                 // pos_sq + posT
        int i = (id - 3078) * 256 + t;
        int b = i >> 11, j = i & (N_ - 1);
        const float4* p = (const float4*)(pos + (size_t)i * PD_);
        float4 a0 = p[0], a1 = p[1], a2 = p[2], a3 = p[3];
        float pv[16] = {a0.x,a0.y,a0.z,a0.w, a1.x,a1.y,a1.z,a1.w,
                        a2.x,a2.y,a2.z,a2.w, a3.x,a3.y,a3.z,a3.w};
        float s = 0.f;
#pragma unroll
        for (int d = 0; d < 16; d++) s += pv[d]*pv[d];
        pos_sq[i] = s;
        float* pT = posT + (size_t)b * 16 * N_;
#pragma unroll
        for (int d = 0; d < 16; d++) pT[d * N_ + j] = pv[d];
        return;
    }
    if (id >= 3072) {                 // bias pack
        int i = (id - 3072) * 256 + t;
        if (i < DIM_)            qkv_b[i] = bq[i];
        else if (i < 2*DIM_)     qkv_b[i] = bk[i - DIM_];
        else                     qkv_b[i] = bv[i - 2*DIM_];
        return;
    }

    const float* W; unsigned short* Wt; int Kd, Nw, nx, ti;
    if      (id < 256)  { W = Wq; Wt = qkvWt;               Kd = 512;  Nw = 512;  nx = 16; ti = id; }
    else if (id < 512)  { W = Wk; Wt = qkvWt + 512*512;     Kd = 512;  Nw = 512;  nx = 16; ti = id - 256; }
    else if (id < 768)  { W = Wv; Wt = qkvWt + 2*512*512;   Kd = 512;  Nw = 512;  nx = 16; ti = id - 512; }
    else if (id < 1024) { W = Wo; Wt = WoT;                 Kd = 512;  Nw = 512;  nx = 16; ti = id - 768; }
    else if (id < 2048) { W = W1; Wt = W1T;                 Kd = 512;  Nw = 2048; nx = 64; ti = id - 1024; }
    else                { W = W2; Wt = W2T;                 Kd = 2048; Nw = 512;  nx = 16; ti = id - 2048; }

    __shared__ float tile[32][33];
    int n0 = (ti % nx) * 32, k0 = (ti / nx) * 32;
    int tx = t & 31, ty = t >> 5;
#pragma unroll
    for (int i = 0; i < 32; i += 8)
        tile[ty + i][tx] = W[(size_t)(k0 + ty + i) * Nw + n0 + tx];
    __syncthreads();
#pragma unroll
    for (int i = 0; i < 32; i += 8)
        Wt[(size_t)(n0 + ty + i) * Kd + k0 + tx] = f2bf(tile[tx][ty + i]);
}

// ---------------------------------------------------------------------------
// LayerNorm standalone (LN2)
// ---------------------------------------------------------------------------
__global__ void layernorm_kernel(const float* __restrict__ x,
                                 const float* __restrict__ scale,
                                 const float* __restrict__ bias,
                                 unsigned short* __restrict__ y)
{
    int wave = (blockIdx.x * blockDim.x + threadIdx.x) >> 6;
    int lane = threadIdx.x & 63;
    if (wave >= TOK_) return;
    const float* xr = x + (size_t)wave * DIM_;
    float v[8];
    float s = 0.f;
#pragma unroll
    for (int i = 0; i < 8; i++) { v[i] = xr[lane + i*64]; s += v[i]; }
#pragma unroll
    for (int off = 32; off; off >>= 1) s += __shfl_xor(s, off);
    float mean = s * (1.f / DIM_);
    float vs = 0.f;
#pragma unroll
    for (int i = 0; i < 8; i++) { float d = v[i] - mean; vs += d*d; }
#pragma unroll
    for (int off = 32; off; off >>= 1) vs += __shfl_xor(vs, off);
    float inv = rsqrtf(vs * (1.f / DIM_) + 1e-6f);
    unsigned short* yr = y + (size_t)wave * DIM_;
#pragma unroll
    for (int i = 0; i < 8; i++) {
        int c = lane + i*64;
        yr[c] = f2bf((v[i] - mean) * inv * scale[c] + bias[c]);
    }
}

// ---------------------------------------------------------------------------
// Sparse attention with bf16 K/V. One wave per (b,h,i).
// ---------------------------------------------------------------------------
__global__ __launch_bounds__(256)
void attn_kernel(const float* __restrict__ q,
                 const unsigned short* __restrict__ kv,
                 const int* __restrict__ topk_idx, const float* __restrict__ topk_dist,
                 const float* __restrict__ log_tau_p, const float* __restrict__ attn_scale_p,
                 unsigned int* __restrict__ out)   // bf16 pairs
{
    int gw   = (blockIdx.x * blockDim.x + threadIdx.x) >> 6;
    int lane = threadIdx.x & 63;
    if (gw >= B_ * NH_ * N_) return;
    int b = gw / (NH_ * N_);
    int r = gw % (NH_ * N_);
    int h = r / N_;
    int i = r % N_;
    int tok = b * N_ + i;

    float tau    = fmaxf(__expf(*log_tau_p), 1e-8f);
    float ascale = *attn_scale_p;

    const int*   idxp = topk_idx  + (size_t)tok * K_;
    const float* dstp = topk_dist + (size_t)tok * K_;
    int   my_idx  = idxp[lane & 31];
    float my_dist = dstp[lane & 31];

    int jj   = lane >> 1;
    int half = lane & 1;

    // q half: 32 floats
    const float4* qp = (const float4*)(q + (size_t)tok * DIM_ + h * HD_ + half * 32);
    float4 qv[8];
#pragma unroll
    for (int u = 0; u < 8; u++) qv[u] = qp[u];

    // k half (bf16): 32 shorts = 4 x 16B
    int nb = __shfl(my_idx, jj);
    const uint4* kp = (const uint4*)(kv + (size_t)(b * N_ + nb) * KV_ + h * HD_ + half * 32);
    float dot = 0.f;
#pragma unroll
    for (int u = 0; u < 4; u++) {
        uint4 kw = kp[u];
        dot += qv[2*u].x   * bflo(kw.x) + qv[2*u].y   * bfhi(kw.x)
             + qv[2*u].z   * bflo(kw.y) + qv[2*u].w   * bfhi(kw.y)
             + qv[2*u+1].x * bflo(kw.z) + qv[2*u+1].y * bfhi(kw.z)
             + qv[2*u+1].z * bflo(kw.w) + qv[2*u+1].w * bfhi(kw.w);
    }
    dot += __shfl_xor(dot, 1);   // full dot on both lanes of the pair

    float fs = dot * 0.125f;                        // 1/sqrt(64)
    float gs = -__shfl(my_dist, jj) / tau;
    float s  = ascale * tanh_fast(fs + gs);

    // softmax over the 32 scores (each duplicated on a lane pair)
    float mx = s;
#pragma unroll
    for (int off = 32; off; off >>= 1) mx = fmaxf(mx, __shfl_xor(mx, off));
    float e  = __expf(s - mx);
    float ec = half ? 0.f : e;
#pragma unroll
    for (int off = 32; off; off >>= 1) ec += __shfl_xor(ec, off);
    float inv = 1.f / ec;

    // V phase: dim pair d2 = 2*(lane&31); lane>=32 handles odd neighbors
    int dp    = lane & 31;
    int half2 = lane >> 5;
    const unsigned int* vb = (const unsigned int*)(kv + DIM_ + h * HD_) + dp;
    float ax = 0.f, ay = 0.f;
#pragma unroll
    for (int it = 0; it < 16; it++) {
        int t2 = half2 + 2*it;
        float w  = __shfl(e, t2 * 2) * inv;
        int   nj = __shfl(my_idx, t2);
        unsigned vv = vb[(size_t)(b * N_ + nj) * (KV_/2)];
        ax += w * bflo(vv);
        ay += w * bfhi(vv);
    }
    ax += __shfl_xor(ax, 32);
    ay += __shfl_xor(ay, 32);
    if (lane < 32) {
        unsigned pck = ((unsigned)f2bf(ay) << 16) | (unsigned)f2bf(ax);
        out[(size_t)tok * (DIM_/2) + h * (HD_/2) + dp] = pck;
    }
}

// ---------------------------------------------------------------------------
extern "C" void kernel_launch(void* const* d_in, const int* in_sizes, int n_in,
                              void* d_out, int out_size, void* d_ws, size_t ws_size,
                              hipStream_t stream)
{
    const float* x          = (const float*)d_in[0];
    const float* positions  = (const float*)d_in[1];
    const float* c_p        = (const float*)d_in[2];
    const float* Wq         = (const float*)d_in[3];
    const float* bq         = (const float*)d_in[4];
    const float* Wk         = (const float*)d_in[5];
    const float* bk         = (const float*)d_in[6];
    const float* Wv         = (const float*)d_in[7];
    const float* bv         = (const float*)d_in[8];
    const float* Wo         = (const float*)d_in[9];
    const float* bo         = (const float*)d_in[10];
    const float* W1         = (const float*)d_in[11];
    const float* b1         = (const float*)d_in[12];
    const float* W2         = (const float*)d_in[13];
    const float* b2         = (const float*)d_in[14];
    const float* ln1_scale  = (const float*)d_in[15];
    const float* ln1_bias   = (const float*)d_in[16];
    const float* ln2_scale  = (const float*)d_in[17];
    const float* ln2_bias   = (const float*)d_in[18];
    const float* log_tau    = (const float*)d_in[19];
    const float* attn_scale = (const float*)d_in[20];

    char* p = (char*)d_ws;
    unsigned short* qkvWt  = (unsigned short*)p; p += (size_t)QKV_ * DIM_ * 2;   // [1536][512] bf16
    unsigned short* WoT    = (unsigned short*)p; p += (size_t)DIM_ * DIM_ * 2;   // [512][512]
    unsigned short* W1T    = (unsigned short*)p; p += (size_t)FFN_ * DIM_ * 2;   // [2048][512]
    unsigned short* W2T    = (unsigned short*)p; p += (size_t)DIM_ * FFN_ * 2;   // [512][2048]
    float*          qkv_b  = (float*)p;          p += (size_t)QKV_ * 4;
    unsigned short* xn     = (unsigned short*)p; p += (size_t)TOK_ * DIM_ * 2;   // bf16
    float*          qf     = (float*)p;          p += (size_t)TOK_ * DIM_ * 4;   // fp32 q
    unsigned short* kvb    = (unsigned short*)p; p += (size_t)TOK_ * KV_ * 2;    // bf16 k|v
    unsigned short* attn_o = (unsigned short*)p; p += (size_t)TOK_ * DIM_ * 2;   // bf16
    float*          x1     = (float*)p;          p += (size_t)TOK_ * DIM_ * 4;
    unsigned short* x2n    = (unsigned short*)p; p += (size_t)TOK_ * DIM_ * 2;
    unsigned short* hbuf   = (unsigned short*)p; p += (size_t)TOK_ * FFN_ * 2;
    float*          pos_sq = (float*)p;          p += (size_t)TOK_ * 4;
    float*          posT   = (float*)p;          p += (size_t)B_ * 16 * N_ * 4;
    float*          tk_d   = (float*)p;          p += (size_t)TOK_ * K_ * 4;
    int*            tk_i   = (int*)p;            p += (size_t)TOK_ * K_ * 4;

    // --- fused prep: transposes + bias + pos_sq/posT + LN1 ---
    fused_prep_kernel<<<4118, 256, 0, stream>>>(Wq, Wk, Wv, Wo, W1, W2, bq, bk, bv,
                                                qkvWt, WoT, W1T, W2T, qkv_b,
                                                positions, pos_sq, posT,
                                                x, ln1_scale, ln1_bias, xn);

    // --- QKV GEMM: 64x128 tiles -> 768 blocks (3/CU) ---
    gemm_bf16_kernel<3,64,128><<<dim3(QKV_/128, TOK_/64), 256, 0, stream>>>(
        xn, qkvWt, qkv_b, nullptr, qf, kvb, QKV_, DIM_);

    // --- distances + top-k (2 waves/row, coalesced float4 posT) ---
    dist_topk_split_kernel<<<TOK_/2, 256, 0, stream>>>(positions, posT, pos_sq,
                                                       c_p, tk_i, tk_d);

    // --- sparse attention -> bf16 ---
    attn_kernel<<<(B_*NH_*N_)/4, 256, 0, stream>>>(qf, kvb, tk_i, tk_d,
                                                   log_tau, attn_scale,
                                                   (unsigned int*)attn_o);

    // --- x1 = x + attn_o @ Wo + bo (fp32), 64x64 -> 512 blocks ---
    gemm_bf16_kernel<1,64,64><<<dim3(DIM_/64, TOK_/64), 256, 0, stream>>>(
        attn_o, WoT, bo, x, x1, nullptr, DIM_, DIM_);

    // --- LN2 -> bf16 ---
    layernorm_kernel<<<TOK_/4, 256, 0, stream>>>(x1, ln2_scale, ln2_bias, x2n);

    // --- FFN1: gelu(x2n @ W1 + b1) -> bf16 h, 64x128 -> 1024 blocks ---
    gemm_bf16_kernel<2,64,128><<<dim3(FFN_/128, TOK_/64), 256, 0, stream>>>(
        x2n, W1T, b1, nullptr, nullptr, hbuf, FFN_, DIM_);

    // --- FFN2: out = x1 + h @ W2 + b2 (fp32), 64x64 -> 512 blocks ---
    gemm_bf16_kernel<1,64,64><<<dim3(DIM_/64, TOK_/64), 256, 0, stream>>>(
        hbuf, W2T, b2, x1, (float*)d_out, nullptr, DIM_, FFN_);
}